// Round 6
// baseline (246.901 us; speedup 1.0000x reference)
//
#include <hip/hip_runtime.h>
#include <math.h>

#define REG_PARAM 0.0002f
#define COS_EPS 1e-8f
#define INV_N (1.0f / 6291456.0f)

#define MEM_BLOCKS 32               // blocks [0,32): mem-cosine path (front of grid)
#define MAIN_BLOCKS 2048            // blocks [32,2080): MSE + entropy fused
#define TOTAL_BLOCKS (MEM_BLOCKS + MAIN_BLOCKS)
#define MSE_STRIDE (MAIN_BLOCKS * 256)   // 524288 float4s; n4 = 3*MSE_STRIDE exactly

// Workspace float layout (all data slots written unconditionally every call):
// [0,2048)            combined main partials: mse_p*INV_N - REG*ent_p
// [2048,2080)         diag partials (mem blocks)
// [2176]              ticket counter (memset to 0 each call by a graph node)
// [2304,2304+32*256)  column-sum partials [32][256]
#define WS_MAIN 0
#define WS_DIAG 2048
#define WS_CTR  2176
#define WS_COL  2304

__device__ __forceinline__ float waveReduceSum(float v) {
    #pragma unroll
    for (int off = 32; off > 0; off >>= 1)
        v += __shfl_xor(v, off, 64);
    return v;
}

__device__ __forceinline__ float blockReduceSum(float v, float* sh) {
    v = waveReduceSum(v);
    int wid = threadIdx.x >> 6, lane = threadIdx.x & 63;
    __syncthreads();
    if (lane == 0) sh[wid] = v;
    __syncthreads();
    return sh[0] + sh[1] + sh[2] + sh[3];
}

__global__ void partials_kernel(const float4* __restrict__ out4,
                                const float4* __restrict__ gt4,
                                const float4* __restrict__ att4,
                                const float4* __restrict__ mem4,
                                float* __restrict__ ws,
                                float* __restrict__ out) {
    __shared__ float sh[4 * 256];   // mem path uses all 1024; main path uses [0,8)
    __shared__ float shd[4];
    __shared__ bool amLast;
    const int t = threadIdx.x;
    const int wid = t >> 6, lane = t & 63;

    if (blockIdx.x >= MEM_BLOCKS) {
        // ---- main: 3 MSE float4-pairs + 1 entropy row per wave, fully unrolled ----
        const int b = blockIdx.x - MEM_BLOCKS;       // 0..2047
        const int base = (b << 8) + t;
        float4 a0 = out4[base];
        float4 g0 = gt4 [base];
        float4 a1 = out4[base + MSE_STRIDE];
        float4 g1 = gt4 [base + MSE_STRIDE];
        float4 a2 = out4[base + 2 * MSE_STRIDE];
        float4 g2 = gt4 [base + 2 * MSE_STRIDE];
        const int row = (b << 2) + wid;              // rows 0..8191 exactly once
        const float4* __restrict__ rp = att4 + (size_t)row * 500;
        float4 x0 = rp[lane];
        float4 x1 = rp[lane + 64];
        float4 x2 = rp[lane + 128];
        float4 x3 = rp[lane + 192];
        float4 x4 = rp[lane + 256];
        float4 x5 = rp[lane + 320];
        float4 x6 = rp[lane + 384];
        float4 x7 = rp[(lane + 448 < 500) ? (lane + 448) : 499];  // clamped addr

        float mse_acc = 0.f, d;
        d = g0.x - a0.x; mse_acc += d * d;
        d = g0.y - a0.y; mse_acc += d * d;
        d = g0.z - a0.z; mse_acc += d * d;
        d = g0.w - a0.w; mse_acc += d * d;
        d = g1.x - a1.x; mse_acc += d * d;
        d = g1.y - a1.y; mse_acc += d * d;
        d = g1.z - a1.z; mse_acc += d * d;
        d = g1.w - a1.w; mse_acc += d * d;
        d = g2.x - a2.x; mse_acc += d * d;
        d = g2.y - a2.y; mse_acc += d * d;
        d = g2.z - a2.z; mse_acc += d * d;
        d = g2.w - a2.w; mse_acc += d * d;

        float z = 0.f, tt = 0.f, e;
        e = __expf(x0.x); z += e; tt += x0.x * e;
        e = __expf(x0.y); z += e; tt += x0.y * e;
        e = __expf(x0.z); z += e; tt += x0.z * e;
        e = __expf(x0.w); z += e; tt += x0.w * e;
        e = __expf(x1.x); z += e; tt += x1.x * e;
        e = __expf(x1.y); z += e; tt += x1.y * e;
        e = __expf(x1.z); z += e; tt += x1.z * e;
        e = __expf(x1.w); z += e; tt += x1.w * e;
        e = __expf(x2.x); z += e; tt += x2.x * e;
        e = __expf(x2.y); z += e; tt += x2.y * e;
        e = __expf(x2.z); z += e; tt += x2.z * e;
        e = __expf(x2.w); z += e; tt += x2.w * e;
        e = __expf(x3.x); z += e; tt += x3.x * e;
        e = __expf(x3.y); z += e; tt += x3.y * e;
        e = __expf(x3.z); z += e; tt += x3.z * e;
        e = __expf(x3.w); z += e; tt += x3.w * e;
        e = __expf(x4.x); z += e; tt += x4.x * e;
        e = __expf(x4.y); z += e; tt += x4.y * e;
        e = __expf(x4.z); z += e; tt += x4.z * e;
        e = __expf(x4.w); z += e; tt += x4.w * e;
        e = __expf(x5.x); z += e; tt += x5.x * e;
        e = __expf(x5.y); z += e; tt += x5.y * e;
        e = __expf(x5.z); z += e; tt += x5.z * e;
        e = __expf(x5.w); z += e; tt += x5.w * e;
        e = __expf(x6.x); z += e; tt += x6.x * e;
        e = __expf(x6.y); z += e; tt += x6.y * e;
        e = __expf(x6.z); z += e; tt += x6.z * e;
        e = __expf(x6.w); z += e; tt += x6.w * e;
        if (lane + 448 < 500) {
            e = __expf(x7.x); z += e; tt += x7.x * e;
            e = __expf(x7.y); z += e; tt += x7.y * e;
            e = __expf(x7.z); z += e; tt += x7.z * e;
            e = __expf(x7.w); z += e; tt += x7.w * e;
        }
        z = waveReduceSum(z);
        tt = waveReduceSum(tt);
        float ent = tt / z - __logf(z);              // sum_j p*logp for this row

        mse_acc = waveReduceSum(mse_acc);
        if (lane == 0) { sh[wid] = mse_acc; sh[4 + wid] = ent; }
        __syncthreads();
        if (t == 0) {
            ws[WS_MAIN + b] = (sh[0] + sh[1] + sh[2] + sh[3]) * INV_N
                            - REG_PARAM * (sh[4] + sh[5] + sh[6] + sh[7]);
        }
    } else {
        // ---- mem: wave-per-row normalize; per-lane column accumulators ----
        const int mb = blockIdx.x;                           // 0..31
        const int wglobal = mb * 4 + wid;                    // 0..127
        float c0 = 0.f, c1 = 0.f, c2 = 0.f, c3 = 0.f, dacc = 0.f;
        for (int row = wglobal; row < 2000; row += MEM_BLOCKS * 4) {
            float4 v = mem4[(size_t)row * 64 + lane];        // cols 4*lane..4*lane+3
            float ss = v.x * v.x + v.y * v.y + v.z * v.z + v.w * v.w;
            ss = waveReduceSum(ss);
            float inv = 1.f / fmaxf(sqrtf(ss), COS_EPS);
            c0 += v.x * inv; c1 += v.y * inv; c2 += v.z * inv; c3 += v.w * inv;
            if (lane == 0) dacc += ss * inv * inv;           // gram diagonal (==1 normally)
        }
        if (lane == 0) shd[wid] = dacc;
        sh[wid * 256 + lane * 4 + 0] = c0;
        sh[wid * 256 + lane * 4 + 1] = c1;
        sh[wid * 256 + lane * 4 + 2] = c2;
        sh[wid * 256 + lane * 4 + 3] = c3;
        __syncthreads();
        ws[WS_COL + mb * 256 + t] = sh[t] + sh[256 + t] + sh[512 + t] + sh[768 + t];
        if (t == 0) ws[WS_DIAG + mb] = shd[0] + shd[1] + shd[2] + shd[3];
    }

    // ---- last-block-done fused finalize (threadfence-reduction pattern) ----
    __threadfence();                 // make this block's partials device-visible
    __syncthreads();                 // all stores+fences done before ticket
    if (t == 0) {
        unsigned int ticket = atomicAdd((unsigned int*)&ws[WS_CTR], 1u);
        amLast = (ticket == TOTAL_BLOCKS - 1);
    }
    __syncthreads();
    if (!amLast) return;
    __threadfence();                 // acquire: order reads after observing all tickets

    {
        __shared__ float shf[4];
        float v = 0.f;
        #pragma unroll
        for (int k = 0; k < 8; ++k) v += ws[WS_MAIN + t + (k << 8)];
        float mainsum = blockReduceSum(v, shf);

        float S = 0.f;
        #pragma unroll
        for (int mb = 0; mb < 32; ++mb) S += ws[WS_COL + (mb << 8) + t];
        float ssum = blockReduceSum(S * S, shf);     // ||S||^2

        float dv = (t < 32) ? ws[WS_DIAG + t] : 0.f;
        float diag = blockReduceSum(dv, shf);

        if (t == 0) {
            out[0] = mainsum + 0.5f * (ssum - diag);
        }
    }
}

extern "C" void kernel_launch(void* const* d_in, const int* in_sizes, int n_in,
                              void* d_out, int out_size, void* d_ws, size_t ws_size,
                              hipStream_t stream) {
    const float* out_img = (const float*)d_in[0];   // (32,3,256,256)
    const float* gt      = (const float*)d_in[1];   // (32,3,256,256)
    const float* att     = (const float*)d_in[2];   // (8192,2000)
    const float* mem     = (const float*)d_in[3];   // (2000,256)
    float* ws = (float*)d_ws;
    float* out = (float*)d_out;

    // Reset the ticket counter (4 bytes) each call; graph-capture-safe.
    hipMemsetAsync((char*)d_ws + WS_CTR * sizeof(float), 0, sizeof(unsigned int), stream);

    partials_kernel<<<TOTAL_BLOCKS, 256, 0, stream>>>(
        (const float4*)out_img, (const float4*)gt,
        (const float4*)att, (const float4*)mem, ws, out);
}

// Round 7
// 48.221 us; speedup vs baseline: 5.1202x; 5.1202x over previous
//
#include <hip/hip_runtime.h>
#include <math.h>

#define REG_PARAM 0.0002f
#define COS_EPS 1e-8f
#define INV_N (1.0f / 6291456.0f)

#define MEM_BLOCKS 32               // blocks [0,32): mem-cosine path (front of grid)
#define MAIN_BLOCKS 2048            // blocks [32,2080): MSE + entropy fused
#define TOTAL_BLOCKS (MEM_BLOCKS + MAIN_BLOCKS)
#define MSE_STRIDE (MAIN_BLOCKS * 256)   // 524288 float4s; n4 = 3*MSE_STRIDE exactly

// Workspace float layout. All cross-block data moves through device-scope
// (AGENT) atomic loads/stores -> served at the coherent point, NO fences,
// NO buffer_wbl2 (round-6 lesson: __threadfence() on gfx950 = L2 writeback
// per block = 300+ us disaster).
// [0,2048)            combined main partials: mse_p*INV_N - REG*ent_p
// [2048,2080)         diag partials (mem blocks)
// [2176]              ticket counter (memset to 0 each call by a graph node)
// [2304,2304+32*256)  column-sum partials [32][256]
#define WS_MAIN 0
#define WS_DIAG 2048
#define WS_CTR  2176
#define WS_COL  2304

#define ASTORE(p, v) __hip_atomic_store((p), (v), __ATOMIC_RELAXED, __HIP_MEMORY_SCOPE_AGENT)
#define ALOAD(p)     __hip_atomic_load((p), __ATOMIC_RELAXED, __HIP_MEMORY_SCOPE_AGENT)

__device__ __forceinline__ float waveReduceSum(float v) {
    #pragma unroll
    for (int off = 32; off > 0; off >>= 1)
        v += __shfl_xor(v, off, 64);
    return v;
}

__device__ __forceinline__ float blockReduceSum(float v, float* sh) {
    v = waveReduceSum(v);
    int wid = threadIdx.x >> 6, lane = threadIdx.x & 63;
    __syncthreads();
    if (lane == 0) sh[wid] = v;
    __syncthreads();
    return sh[0] + sh[1] + sh[2] + sh[3];
}

__global__ void partials_kernel(const float4* __restrict__ out4,
                                const float4* __restrict__ gt4,
                                const float4* __restrict__ att4,
                                const float4* __restrict__ mem4,
                                float* __restrict__ ws,
                                float* __restrict__ out) {
    __shared__ float sh[4 * 256];   // mem path uses all 1024; main path uses [0,8)
    __shared__ float shd[4];
    __shared__ bool amLast;
    const int t = threadIdx.x;
    const int wid = t >> 6, lane = t & 63;

    if (blockIdx.x >= MEM_BLOCKS) {
        // ---- main: 3 MSE float4-pairs + 1 entropy row per wave, fully unrolled ----
        const int b = blockIdx.x - MEM_BLOCKS;       // 0..2047
        const int base = (b << 8) + t;
        float4 a0 = out4[base];
        float4 g0 = gt4 [base];
        float4 a1 = out4[base + MSE_STRIDE];
        float4 g1 = gt4 [base + MSE_STRIDE];
        float4 a2 = out4[base + 2 * MSE_STRIDE];
        float4 g2 = gt4 [base + 2 * MSE_STRIDE];
        const int row = (b << 2) + wid;              // rows 0..8191 exactly once
        const float4* __restrict__ rp = att4 + (size_t)row * 500;
        float4 x0 = rp[lane];
        float4 x1 = rp[lane + 64];
        float4 x2 = rp[lane + 128];
        float4 x3 = rp[lane + 192];
        float4 x4 = rp[lane + 256];
        float4 x5 = rp[lane + 320];
        float4 x6 = rp[lane + 384];
        float4 x7 = rp[(lane + 448 < 500) ? (lane + 448) : 499];  // clamped addr

        float mse_acc = 0.f, d;
        d = g0.x - a0.x; mse_acc += d * d;
        d = g0.y - a0.y; mse_acc += d * d;
        d = g0.z - a0.z; mse_acc += d * d;
        d = g0.w - a0.w; mse_acc += d * d;
        d = g1.x - a1.x; mse_acc += d * d;
        d = g1.y - a1.y; mse_acc += d * d;
        d = g1.z - a1.z; mse_acc += d * d;
        d = g1.w - a1.w; mse_acc += d * d;
        d = g2.x - a2.x; mse_acc += d * d;
        d = g2.y - a2.y; mse_acc += d * d;
        d = g2.z - a2.z; mse_acc += d * d;
        d = g2.w - a2.w; mse_acc += d * d;

        float z = 0.f, tt = 0.f, e;
        e = __expf(x0.x); z += e; tt += x0.x * e;
        e = __expf(x0.y); z += e; tt += x0.y * e;
        e = __expf(x0.z); z += e; tt += x0.z * e;
        e = __expf(x0.w); z += e; tt += x0.w * e;
        e = __expf(x1.x); z += e; tt += x1.x * e;
        e = __expf(x1.y); z += e; tt += x1.y * e;
        e = __expf(x1.z); z += e; tt += x1.z * e;
        e = __expf(x1.w); z += e; tt += x1.w * e;
        e = __expf(x2.x); z += e; tt += x2.x * e;
        e = __expf(x2.y); z += e; tt += x2.y * e;
        e = __expf(x2.z); z += e; tt += x2.z * e;
        e = __expf(x2.w); z += e; tt += x2.w * e;
        e = __expf(x3.x); z += e; tt += x3.x * e;
        e = __expf(x3.y); z += e; tt += x3.y * e;
        e = __expf(x3.z); z += e; tt += x3.z * e;
        e = __expf(x3.w); z += e; tt += x3.w * e;
        e = __expf(x4.x); z += e; tt += x4.x * e;
        e = __expf(x4.y); z += e; tt += x4.y * e;
        e = __expf(x4.z); z += e; tt += x4.z * e;
        e = __expf(x4.w); z += e; tt += x4.w * e;
        e = __expf(x5.x); z += e; tt += x5.x * e;
        e = __expf(x5.y); z += e; tt += x5.y * e;
        e = __expf(x5.z); z += e; tt += x5.z * e;
        e = __expf(x5.w); z += e; tt += x5.w * e;
        e = __expf(x6.x); z += e; tt += x6.x * e;
        e = __expf(x6.y); z += e; tt += x6.y * e;
        e = __expf(x6.z); z += e; tt += x6.z * e;
        e = __expf(x6.w); z += e; tt += x6.w * e;
        if (lane + 448 < 500) {
            e = __expf(x7.x); z += e; tt += x7.x * e;
            e = __expf(x7.y); z += e; tt += x7.y * e;
            e = __expf(x7.z); z += e; tt += x7.z * e;
            e = __expf(x7.w); z += e; tt += x7.w * e;
        }
        z = waveReduceSum(z);
        tt = waveReduceSum(tt);
        float ent = tt / z - __logf(z);              // sum_j p*logp for this row

        mse_acc = waveReduceSum(mse_acc);
        if (lane == 0) { sh[wid] = mse_acc; sh[4 + wid] = ent; }
        __syncthreads();
        if (t == 0) {
            ASTORE(&ws[WS_MAIN + b],
                   (sh[0] + sh[1] + sh[2] + sh[3]) * INV_N
                 - REG_PARAM * (sh[4] + sh[5] + sh[6] + sh[7]));
        }
    } else {
        // ---- mem: wave-per-row normalize; per-lane column accumulators ----
        const int mb = blockIdx.x;                           // 0..31
        const int wglobal = mb * 4 + wid;                    // 0..127
        float c0 = 0.f, c1 = 0.f, c2 = 0.f, c3 = 0.f, dacc = 0.f;
        for (int row = wglobal; row < 2000; row += MEM_BLOCKS * 4) {
            float4 v = mem4[(size_t)row * 64 + lane];        // cols 4*lane..4*lane+3
            float ss = v.x * v.x + v.y * v.y + v.z * v.z + v.w * v.w;
            ss = waveReduceSum(ss);
            float inv = 1.f / fmaxf(sqrtf(ss), COS_EPS);
            c0 += v.x * inv; c1 += v.y * inv; c2 += v.z * inv; c3 += v.w * inv;
            if (lane == 0) dacc += ss * inv * inv;           // gram diagonal (==1 normally)
        }
        if (lane == 0) shd[wid] = dacc;
        sh[wid * 256 + lane * 4 + 0] = c0;
        sh[wid * 256 + lane * 4 + 1] = c1;
        sh[wid * 256 + lane * 4 + 2] = c2;
        sh[wid * 256 + lane * 4 + 3] = c3;
        __syncthreads();
        ASTORE(&ws[WS_COL + mb * 256 + t],
               sh[t] + sh[256 + t] + sh[512 + t] + sh[768 + t]);
        if (t == 0) ASTORE(&ws[WS_DIAG + mb], shd[0] + shd[1] + shd[2] + shd[3]);
    }

    // ---- last-block-done fused finalize, fence-free ----
    // Per-wave: drain our atomic stores to the coherence point; then barrier
    // (compiler also drains vmcnt before s_barrier). Only after that may t0
    // publish the ticket, so ticket-visibility implies partials-visibility.
    asm volatile("s_waitcnt vmcnt(0)" ::: "memory");
    __syncthreads();
    if (t == 0) {
        unsigned int ticket = __hip_atomic_fetch_add(
            (unsigned int*)&ws[WS_CTR], 1u,
            __ATOMIC_RELAXED, __HIP_MEMORY_SCOPE_AGENT);
        amLast = (ticket == TOTAL_BLOCKS - 1);
    }
    __syncthreads();
    if (!amLast) return;

    {
        __shared__ float shf[4];
        float v = 0.f;
        #pragma unroll
        for (int k = 0; k < 8; ++k) v += ALOAD(&ws[WS_MAIN + t + (k << 8)]);
        float mainsum = blockReduceSum(v, shf);

        float S = 0.f;
        #pragma unroll
        for (int mb = 0; mb < 32; ++mb) S += ALOAD(&ws[WS_COL + (mb << 8) + t]);
        float ssum = blockReduceSum(S * S, shf);     // ||S||^2

        float dv = (t < 32) ? ALOAD(&ws[WS_DIAG + t]) : 0.f;
        float diag = blockReduceSum(dv, shf);

        if (t == 0) {
            out[0] = mainsum + 0.5f * (ssum - diag);
        }
    }
}

extern "C" void kernel_launch(void* const* d_in, const int* in_sizes, int n_in,
                              void* d_out, int out_size, void* d_ws, size_t ws_size,
                              hipStream_t stream) {
    const float* out_img = (const float*)d_in[0];   // (32,3,256,256)
    const float* gt      = (const float*)d_in[1];   // (32,3,256,256)
    const float* att     = (const float*)d_in[2];   // (8192,2000)
    const float* mem     = (const float*)d_in[3];   // (2000,256)
    float* ws = (float*)d_ws;
    float* out = (float*)d_out;

    // Reset the ticket counter (4 bytes) each call; graph-capture-safe.
    hipMemsetAsync((char*)d_ws + WS_CTR * sizeof(float), 0, sizeof(unsigned int), stream);

    partials_kernel<<<TOTAL_BLOCKS, 256, 0, stream>>>(
        (const float4*)out_img, (const float4*)gt,
        (const float4*)att, (const float4*)mem, ws, out);
}

// Round 8
// 35.906 us; speedup vs baseline: 6.8763x; 1.3430x over previous
//
#include <hip/hip_runtime.h>
#include <math.h>

#define REG_PARAM 0.0002f
#define COS_EPS 1e-8f
#define INV_N (1.0f / 6291456.0f)

#define MEM_BLOCKS 32               // blocks [0,32): mem-cosine path (front of grid)
#define MAIN_BLOCKS 2048            // blocks [32,2080): MSE + entropy fused
#define TOTAL_BLOCKS (MEM_BLOCKS + MAIN_BLOCKS)   // 2080 = 65 groups * 32 blocks
#define MSE_STRIDE (MAIN_BLOCKS * 256)   // 524288 float4s; n4 = 3*MSE_STRIDE exactly
#define GROUPS 65

// Workspace float layout. Cross-block data via AGENT-scope atomic load/store
// (write-through to the coherence point, no fences -> no buffer_wbl2; round-6
// lesson). Completion via a TWO-LEVEL ticket tree (round-7 lesson: one flat
// counter = 2080 same-address atomics = ~27us serialized on the critical path;
// two levels cap it at ~1.4us).
// [0,2048)            combined main partials: mse_p*INV_N - REG*ent_p
// [2048,2080)         diag partials (mem blocks)
// [2112,3152)         65 group counters, stride 16 floats (64B) each
// [3152]              root counter
// [3200,3200+32*256)  column-sum partials [32][256]
#define WS_MAIN 0
#define WS_DIAG 2048
#define WS_CTR1 2112
#define WS_CTR2 3152
#define WS_COL  3200

#define ASTORE(p, v) __hip_atomic_store((p), (v), __ATOMIC_RELAXED, __HIP_MEMORY_SCOPE_AGENT)
#define ALOAD(p)     __hip_atomic_load((p), __ATOMIC_RELAXED, __HIP_MEMORY_SCOPE_AGENT)

__device__ __forceinline__ float waveReduceSum(float v) {
    #pragma unroll
    for (int off = 32; off > 0; off >>= 1)
        v += __shfl_xor(v, off, 64);
    return v;
}

__device__ __forceinline__ float blockReduceSum(float v, float* sh) {
    v = waveReduceSum(v);
    int wid = threadIdx.x >> 6, lane = threadIdx.x & 63;
    __syncthreads();
    if (lane == 0) sh[wid] = v;
    __syncthreads();
    return sh[0] + sh[1] + sh[2] + sh[3];
}

__global__ void partials_kernel(const float4* __restrict__ out4,
                                const float4* __restrict__ gt4,
                                const float4* __restrict__ att4,
                                const float4* __restrict__ mem4,
                                float* __restrict__ ws,
                                float* __restrict__ out) {
    __shared__ float sh[4 * 256];   // mem path uses all 1024; main path uses [0,8)
    __shared__ float shd[4];
    __shared__ bool amLast;
    const int t = threadIdx.x;
    const int wid = t >> 6, lane = t & 63;

    if (blockIdx.x >= MEM_BLOCKS) {
        // ---- main: 3 MSE float4-pairs + 1 entropy row per wave, fully unrolled ----
        const int b = blockIdx.x - MEM_BLOCKS;       // 0..2047
        const int base = (b << 8) + t;
        float4 a0 = out4[base];
        float4 g0 = gt4 [base];
        float4 a1 = out4[base + MSE_STRIDE];
        float4 g1 = gt4 [base + MSE_STRIDE];
        float4 a2 = out4[base + 2 * MSE_STRIDE];
        float4 g2 = gt4 [base + 2 * MSE_STRIDE];
        const int row = (b << 2) + wid;              // rows 0..8191 exactly once
        const float4* __restrict__ rp = att4 + (size_t)row * 500;
        float4 x0 = rp[lane];
        float4 x1 = rp[lane + 64];
        float4 x2 = rp[lane + 128];
        float4 x3 = rp[lane + 192];
        float4 x4 = rp[lane + 256];
        float4 x5 = rp[lane + 320];
        float4 x6 = rp[lane + 384];
        float4 x7 = rp[(lane + 448 < 500) ? (lane + 448) : 499];  // clamped addr

        float mse_acc = 0.f, d;
        d = g0.x - a0.x; mse_acc += d * d;
        d = g0.y - a0.y; mse_acc += d * d;
        d = g0.z - a0.z; mse_acc += d * d;
        d = g0.w - a0.w; mse_acc += d * d;
        d = g1.x - a1.x; mse_acc += d * d;
        d = g1.y - a1.y; mse_acc += d * d;
        d = g1.z - a1.z; mse_acc += d * d;
        d = g1.w - a1.w; mse_acc += d * d;
        d = g2.x - a2.x; mse_acc += d * d;
        d = g2.y - a2.y; mse_acc += d * d;
        d = g2.z - a2.z; mse_acc += d * d;
        d = g2.w - a2.w; mse_acc += d * d;

        float z = 0.f, tt = 0.f, e;
        e = __expf(x0.x); z += e; tt += x0.x * e;
        e = __expf(x0.y); z += e; tt += x0.y * e;
        e = __expf(x0.z); z += e; tt += x0.z * e;
        e = __expf(x0.w); z += e; tt += x0.w * e;
        e = __expf(x1.x); z += e; tt += x1.x * e;
        e = __expf(x1.y); z += e; tt += x1.y * e;
        e = __expf(x1.z); z += e; tt += x1.z * e;
        e = __expf(x1.w); z += e; tt += x1.w * e;
        e = __expf(x2.x); z += e; tt += x2.x * e;
        e = __expf(x2.y); z += e; tt += x2.y * e;
        e = __expf(x2.z); z += e; tt += x2.z * e;
        e = __expf(x2.w); z += e; tt += x2.w * e;
        e = __expf(x3.x); z += e; tt += x3.x * e;
        e = __expf(x3.y); z += e; tt += x3.y * e;
        e = __expf(x3.z); z += e; tt += x3.z * e;
        e = __expf(x3.w); z += e; tt += x3.w * e;
        e = __expf(x4.x); z += e; tt += x4.x * e;
        e = __expf(x4.y); z += e; tt += x4.y * e;
        e = __expf(x4.z); z += e; tt += x4.z * e;
        e = __expf(x4.w); z += e; tt += x4.w * e;
        e = __expf(x5.x); z += e; tt += x5.x * e;
        e = __expf(x5.y); z += e; tt += x5.y * e;
        e = __expf(x5.z); z += e; tt += x5.z * e;
        e = __expf(x5.w); z += e; tt += x5.w * e;
        e = __expf(x6.x); z += e; tt += x6.x * e;
        e = __expf(x6.y); z += e; tt += x6.y * e;
        e = __expf(x6.z); z += e; tt += x6.z * e;
        e = __expf(x6.w); z += e; tt += x6.w * e;
        if (lane + 448 < 500) {
            e = __expf(x7.x); z += e; tt += x7.x * e;
            e = __expf(x7.y); z += e; tt += x7.y * e;
            e = __expf(x7.z); z += e; tt += x7.z * e;
            e = __expf(x7.w); z += e; tt += x7.w * e;
        }
        z = waveReduceSum(z);
        tt = waveReduceSum(tt);
        float ent = tt / z - __logf(z);              // sum_j p*logp for this row

        mse_acc = waveReduceSum(mse_acc);
        if (lane == 0) { sh[wid] = mse_acc; sh[4 + wid] = ent; }
        __syncthreads();
        if (t == 0) {
            ASTORE(&ws[WS_MAIN + b],
                   (sh[0] + sh[1] + sh[2] + sh[3]) * INV_N
                 - REG_PARAM * (sh[4] + sh[5] + sh[6] + sh[7]));
        }
    } else {
        // ---- mem: wave-per-row normalize; per-lane column accumulators ----
        const int mb = blockIdx.x;                           // 0..31
        const int wglobal = mb * 4 + wid;                    // 0..127
        float c0 = 0.f, c1 = 0.f, c2 = 0.f, c3 = 0.f, dacc = 0.f;
        for (int row = wglobal; row < 2000; row += MEM_BLOCKS * 4) {
            float4 v = mem4[(size_t)row * 64 + lane];        // cols 4*lane..4*lane+3
            float ss = v.x * v.x + v.y * v.y + v.z * v.z + v.w * v.w;
            ss = waveReduceSum(ss);
            float inv = 1.f / fmaxf(sqrtf(ss), COS_EPS);
            c0 += v.x * inv; c1 += v.y * inv; c2 += v.z * inv; c3 += v.w * inv;
            if (lane == 0) dacc += ss * inv * inv;           // gram diagonal (==1 normally)
        }
        if (lane == 0) shd[wid] = dacc;
        sh[wid * 256 + lane * 4 + 0] = c0;
        sh[wid * 256 + lane * 4 + 1] = c1;
        sh[wid * 256 + lane * 4 + 2] = c2;
        sh[wid * 256 + lane * 4 + 3] = c3;
        __syncthreads();
        ASTORE(&ws[WS_COL + mb * 256 + t],
               sh[t] + sh[256 + t] + sh[512 + t] + sh[768 + t]);
        if (t == 0) ASTORE(&ws[WS_DIAG + mb], shd[0] + shd[1] + shd[2] + shd[3]);
    }

    // ---- last-block-done fused finalize, fence-free, two-level ticket ----
    // Drain this block's partial stores to the coherence point, then barrier;
    // only then may t0 take tickets, so ticket-visibility => partials-visibility.
    asm volatile("s_waitcnt vmcnt(0)" ::: "memory");
    __syncthreads();
    if (t == 0) {
        bool last = false;
        const int g = blockIdx.x >> 5;               // 0..64, 32 blocks each
        unsigned int t1 = __hip_atomic_fetch_add(
            (unsigned int*)&ws[WS_CTR1 + g * 16], 1u,
            __ATOMIC_RELAXED, __HIP_MEMORY_SCOPE_AGENT);
        if (t1 == 31) {                              // last in my group
            unsigned int t2 = __hip_atomic_fetch_add(
                (unsigned int*)&ws[WS_CTR2], 1u,
                __ATOMIC_RELAXED, __HIP_MEMORY_SCOPE_AGENT);
            last = (t2 == GROUPS - 1);               // last group overall
        }
        amLast = last;
    }
    __syncthreads();
    if (!amLast) return;

    {
        __shared__ float shf[4];
        float v = 0.f;
        #pragma unroll
        for (int k = 0; k < 8; ++k) v += ALOAD(&ws[WS_MAIN + t + (k << 8)]);
        float mainsum = blockReduceSum(v, shf);

        float S = 0.f;
        #pragma unroll
        for (int mb = 0; mb < 32; ++mb) S += ALOAD(&ws[WS_COL + (mb << 8) + t]);
        float ssum = blockReduceSum(S * S, shf);     // ||S||^2

        float dv = (t < 32) ? ALOAD(&ws[WS_DIAG + t]) : 0.f;
        float diag = blockReduceSum(dv, shf);

        if (t == 0) {
            out[0] = mainsum + 0.5f * (ssum - diag);
        }
    }
}

extern "C" void kernel_launch(void* const* d_in, const int* in_sizes, int n_in,
                              void* d_out, int out_size, void* d_ws, size_t ws_size,
                              hipStream_t stream) {
    const float* out_img = (const float*)d_in[0];   // (32,3,256,256)
    const float* gt      = (const float*)d_in[1];   // (32,3,256,256)
    const float* att     = (const float*)d_in[2];   // (8192,2000)
    const float* mem     = (const float*)d_in[3];   // (2000,256)
    float* ws = (float*)d_ws;
    float* out = (float*)d_out;

    // Reset all ticket counters ([2112,3153) floats) each call; capture-safe.
    hipMemsetAsync((char*)d_ws + WS_CTR1 * sizeof(float), 0,
                   (WS_CTR2 - WS_CTR1 + 1) * sizeof(float), stream);

    partials_kernel<<<TOTAL_BLOCKS, 256, 0, stream>>>(
        (const float4*)out_img, (const float4*)gt,
        (const float4*)att, (const float4*)mem, ws, out);
}

// Round 9
// 29.148 us; speedup vs baseline: 8.4705x; 1.2319x over previous
//
#include <hip/hip_runtime.h>
#include <math.h>

#define REG_PARAM 0.0002f
#define COS_EPS 1e-8f
#define INV_N (1.0f / 6291456.0f)

#define MEM_BLOCKS 32               // blocks [0,32): mem-cosine path (front of grid)
#define MAIN_BLOCKS 2048            // blocks [32,2080): MSE + entropy fused
#define TOTAL_BLOCKS (MEM_BLOCKS + MAIN_BLOCKS)
#define MSE_STRIDE (MAIN_BLOCKS * 256)   // 524288 float4s; n4 = 3*MSE_STRIDE exactly

// Two-kernel form (round-5 structure, measured best). Fusion abandoned:
// round-6 (__threadfence = per-block L2 writeback) = 247us; round-7/8
// (agent-atomics + tickets) = 48/36us; plain two-kernel = 29us. Kernel
// boundary is the cheapest cross-XCD coherence mechanism available.
//
// Workspace float layout (every slot written unconditionally -> no memset):
// [0,2048)            combined main partials: mse_p*INV_N - REG*ent_p
// [2048,2080)         diag partials (mem blocks)
// [2304,2304+32*256)  column-sum partials [32][256]
#define WS_MAIN 0
#define WS_DIAG 2048
#define WS_COL  2304

__device__ __forceinline__ float waveReduceSum(float v) {
    #pragma unroll
    for (int off = 32; off > 0; off >>= 1)
        v += __shfl_xor(v, off, 64);
    return v;
}

__global__ void partials_kernel(const float4* __restrict__ out4,
                                const float4* __restrict__ gt4,
                                const float4* __restrict__ att4,
                                const float4* __restrict__ mem4,
                                float* __restrict__ ws) {
    __shared__ float sh[4 * 256];   // mem path uses all 1024; main path uses [0,8)
    __shared__ float shd[4];
    const int t = threadIdx.x;
    const int wid = t >> 6, lane = t & 63;

    if (blockIdx.x >= MEM_BLOCKS) {
        // ---- main: 3 MSE float4-pairs + 1 entropy row per wave, fully unrolled ----
        const int b = blockIdx.x - MEM_BLOCKS;       // 0..2047
        const int base = (b << 8) + t;
        float4 a0 = out4[base];
        float4 g0 = gt4 [base];
        float4 a1 = out4[base + MSE_STRIDE];
        float4 g1 = gt4 [base + MSE_STRIDE];
        float4 a2 = out4[base + 2 * MSE_STRIDE];
        float4 g2 = gt4 [base + 2 * MSE_STRIDE];
        const int row = (b << 2) + wid;              // rows 0..8191 exactly once
        const float4* __restrict__ rp = att4 + (size_t)row * 500;
        float4 x0 = rp[lane];
        float4 x1 = rp[lane + 64];
        float4 x2 = rp[lane + 128];
        float4 x3 = rp[lane + 192];
        float4 x4 = rp[lane + 256];
        float4 x5 = rp[lane + 320];
        float4 x6 = rp[lane + 384];
        float4 x7 = rp[(lane + 448 < 500) ? (lane + 448) : 499];  // clamped addr

        float mse_acc = 0.f, d;
        d = g0.x - a0.x; mse_acc += d * d;
        d = g0.y - a0.y; mse_acc += d * d;
        d = g0.z - a0.z; mse_acc += d * d;
        d = g0.w - a0.w; mse_acc += d * d;
        d = g1.x - a1.x; mse_acc += d * d;
        d = g1.y - a1.y; mse_acc += d * d;
        d = g1.z - a1.z; mse_acc += d * d;
        d = g1.w - a1.w; mse_acc += d * d;
        d = g2.x - a2.x; mse_acc += d * d;
        d = g2.y - a2.y; mse_acc += d * d;
        d = g2.z - a2.z; mse_acc += d * d;
        d = g2.w - a2.w; mse_acc += d * d;

        float z = 0.f, tt = 0.f, e;
        e = __expf(x0.x); z += e; tt += x0.x * e;
        e = __expf(x0.y); z += e; tt += x0.y * e;
        e = __expf(x0.z); z += e; tt += x0.z * e;
        e = __expf(x0.w); z += e; tt += x0.w * e;
        e = __expf(x1.x); z += e; tt += x1.x * e;
        e = __expf(x1.y); z += e; tt += x1.y * e;
        e = __expf(x1.z); z += e; tt += x1.z * e;
        e = __expf(x1.w); z += e; tt += x1.w * e;
        e = __expf(x2.x); z += e; tt += x2.x * e;
        e = __expf(x2.y); z += e; tt += x2.y * e;
        e = __expf(x2.z); z += e; tt += x2.z * e;
        e = __expf(x2.w); z += e; tt += x2.w * e;
        e = __expf(x3.x); z += e; tt += x3.x * e;
        e = __expf(x3.y); z += e; tt += x3.y * e;
        e = __expf(x3.z); z += e; tt += x3.z * e;
        e = __expf(x3.w); z += e; tt += x3.w * e;
        e = __expf(x4.x); z += e; tt += x4.x * e;
        e = __expf(x4.y); z += e; tt += x4.y * e;
        e = __expf(x4.z); z += e; tt += x4.z * e;
        e = __expf(x4.w); z += e; tt += x4.w * e;
        e = __expf(x5.x); z += e; tt += x5.x * e;
        e = __expf(x5.y); z += e; tt += x5.y * e;
        e = __expf(x5.z); z += e; tt += x5.z * e;
        e = __expf(x5.w); z += e; tt += x5.w * e;
        e = __expf(x6.x); z += e; tt += x6.x * e;
        e = __expf(x6.y); z += e; tt += x6.y * e;
        e = __expf(x6.z); z += e; tt += x6.z * e;
        e = __expf(x6.w); z += e; tt += x6.w * e;
        if (lane + 448 < 500) {
            e = __expf(x7.x); z += e; tt += x7.x * e;
            e = __expf(x7.y); z += e; tt += x7.y * e;
            e = __expf(x7.z); z += e; tt += x7.z * e;
            e = __expf(x7.w); z += e; tt += x7.w * e;
        }
        z = waveReduceSum(z);
        tt = waveReduceSum(tt);
        float ent = tt / z - __logf(z);              // sum_j p*logp for this row

        mse_acc = waveReduceSum(mse_acc);
        if (lane == 0) { sh[wid] = mse_acc; sh[4 + wid] = ent; }
        __syncthreads();
        if (t == 0) {
            ws[WS_MAIN + b] = (sh[0] + sh[1] + sh[2] + sh[3]) * INV_N
                            - REG_PARAM * (sh[4] + sh[5] + sh[6] + sh[7]);
        }
    } else {
        // ---- mem: wave-per-row normalize; per-lane column accumulators ----
        const int mb = blockIdx.x;                           // 0..31
        const int wglobal = mb * 4 + wid;                    // 0..127
        float c0 = 0.f, c1 = 0.f, c2 = 0.f, c3 = 0.f, dacc = 0.f;
        for (int row = wglobal; row < 2000; row += MEM_BLOCKS * 4) {
            float4 v = mem4[(size_t)row * 64 + lane];        // cols 4*lane..4*lane+3
            float ss = v.x * v.x + v.y * v.y + v.z * v.z + v.w * v.w;
            ss = waveReduceSum(ss);
            float inv = 1.f / fmaxf(sqrtf(ss), COS_EPS);
            c0 += v.x * inv; c1 += v.y * inv; c2 += v.z * inv; c3 += v.w * inv;
            if (lane == 0) dacc += ss * inv * inv;           // gram diagonal (==1 normally)
        }
        if (lane == 0) shd[wid] = dacc;
        sh[wid * 256 + lane * 4 + 0] = c0;
        sh[wid * 256 + lane * 4 + 1] = c1;
        sh[wid * 256 + lane * 4 + 2] = c2;
        sh[wid * 256 + lane * 4 + 3] = c3;
        __syncthreads();
        ws[WS_COL + mb * 256 + t] = sh[t] + sh[256 + t] + sh[512 + t] + sh[768 + t];
        if (t == 0) ws[WS_DIAG + mb] = shd[0] + shd[1] + shd[2] + shd[3];
    }
}

// 1024-thread single-block finalize: 11 loads/thread, one latency round.
__global__ void finalize_kernel(const float* __restrict__ ws, float* __restrict__ out) {
    __shared__ float shc[1024];
    __shared__ float shr[16];
    const int t = threadIdx.x;
    const int wid = t >> 6, lane = t & 63;

    // Issue all loads up front (independent).
    float v = ws[WS_MAIN + t] + ws[WS_MAIN + t + 1024];

    const int c = t & 255, s0 = t >> 8;          // 4 threads per column
    float colp = 0.f;
    #pragma unroll
    for (int k = 0; k < 8; ++k)
        colp += ws[WS_COL + ((s0 + (k << 2)) << 8) + c];

    float dv = (t < 32) ? ws[WS_DIAG + t] : 0.f;

    // Combine column partials across the 4 threads sharing column c.
    shc[t] = colp;
    __syncthreads();
    float S = 0.f;
    if (t < 256) S = shc[t] + shc[t + 256] + shc[t + 512] + shc[t + 768];

    // Single 16-wave block reduce of the three dot-products at once.
    float r0 = waveReduceSum(v);
    float r1 = waveReduceSum(S * S);
    float r2 = waveReduceSum(dv);
    __syncthreads();
    if (lane == 0) shr[wid] = r0;
    __syncthreads();
    float mainsum = 0.f;
    if (t == 0) {
        #pragma unroll
        for (int k = 0; k < 16; ++k) mainsum += shr[k];
    }
    __syncthreads();
    if (lane == 0) shr[wid] = r1;
    __syncthreads();
    float ssum = 0.f;
    if (t == 0) {
        #pragma unroll
        for (int k = 0; k < 16; ++k) ssum += shr[k];
    }
    __syncthreads();
    if (lane == 0) shr[wid] = r2;
    __syncthreads();
    if (t == 0) {
        float diag = 0.f;
        #pragma unroll
        for (int k = 0; k < 16; ++k) diag += shr[k];
        out[0] = mainsum + 0.5f * (ssum - diag);
    }
}

extern "C" void kernel_launch(void* const* d_in, const int* in_sizes, int n_in,
                              void* d_out, int out_size, void* d_ws, size_t ws_size,
                              hipStream_t stream) {
    const float* out_img = (const float*)d_in[0];   // (32,3,256,256)
    const float* gt      = (const float*)d_in[1];   // (32,3,256,256)
    const float* att     = (const float*)d_in[2];   // (8192,2000)
    const float* mem     = (const float*)d_in[3];   // (2000,256)
    float* ws = (float*)d_ws;
    float* out = (float*)d_out;

    partials_kernel<<<TOTAL_BLOCKS, 256, 0, stream>>>(
        (const float4*)out_img, (const float4*)gt,
        (const float4*)att, (const float4*)mem, ws);
    finalize_kernel<<<1, 1024, 0, stream>>>(ws, out);
}